// Round 5
// baseline (11614.169 us; speedup 1.0000x reference)
//
#include <hip/hip_runtime.h>
#include <hip/hip_bf16.h>
#include <math.h>

#define B_ 32
#define N_ 256
#define E_ 1024
#define BN_ 8192

typedef __hip_bfloat16 bf16;

__device__ __forceinline__ float b2f(bf16 v) {
    unsigned short u = *(unsigned short*)&v;
    return __uint_as_float(((unsigned)u) << 16);
}
__device__ __forceinline__ unsigned short f2bu(float f) {
    bf16 h = __float2bfloat16(f);
    return *(unsigned short*)&h;
}
__device__ __forceinline__ float4 load4bf(const bf16* p) {
    ushort4 u = *(const ushort4*)p;
    return make_float4(__uint_as_float((unsigned)u.x << 16),
                       __uint_as_float((unsigned)u.y << 16),
                       __uint_as_float((unsigned)u.z << 16),
                       __uint_as_float((unsigned)u.w << 16));
}
__device__ __forceinline__ void store4bf(bf16* p, float a, float b, float c, float d) {
    ushort4 u = make_ushort4(f2bu(a), f2bu(b), f2bu(c), f2bu(d));
    *(ushort4*)p = u;
}
__device__ __forceinline__ float safe_sigm(float x) {
    x = fminf(fmaxf(x, -40.0f), 40.0f);
    return 1.0f / (1.0f + expf(-x));
}
__device__ __forceinline__ float safe_tanh(float x) {
    x = fminf(fmaxf(x, -15.0f), 15.0f);
    float t = expf(2.0f * x);
    return (t - 1.0f) / (t + 1.0f);
}

// ---------------------------------------------------------------------------
// h0 = annotation(8192,18) @ anno_W(18,1024) -> fp32
__global__ __launch_bounds__(256)
void anno_kernel(const float* __restrict__ anno, const float* __restrict__ W,
                 float* __restrict__ H)
{
    __shared__ float s[18];
    int row = blockIdx.x;
    if (threadIdx.x < 18) s[threadIdx.x] = anno[row * 18 + threadIdx.x];
    __syncthreads();
    for (int j = threadIdx.x; j < 1024; j += 256) {
        float acc = 0.0f;
#pragma unroll
        for (int k = 0; k < 18; ++k) acc = fmaf(s[k], W[k * 1024 + j], acc);
        H[(size_t)row * 1024 + j] = acc;
    }
}

// ---------------------------------------------------------------------------
// a = [A_out@H | A_in@H] per batch -> Abuf(8192,2048) bf16
__global__ __launch_bounds__(256)
void bmm_kernel(const float* __restrict__ Aout, const float* __restrict__ Ain,
                const float* __restrict__ H, bf16* __restrict__ Abuf)
{
    __shared__ float As[16][68];
    __shared__ float Bs[16][68];
    const int z = blockIdx.z;
    const int b = z >> 1, which = z & 1;
    const float* Amat = (which ? Ain : Aout) + (size_t)b * N_ * N_;
    const float* Bmat = H + (size_t)b * N_ * E_;
    const int t = threadIdx.x;
    const int tx = t & 15, ty = t >> 4;
    const int bm = blockIdx.x * 64;
    const int bn = blockIdx.y * 64;
    const int ar = t >> 2, ak = (t & 3) << 2;
    const int kr = t >> 4, kn = (t & 15) << 2;
    float acc[4][4] = {};
    for (int k0 = 0; k0 < N_; k0 += 16) {
        float4 av = *(const float4*)(Amat + (size_t)(bm + ar) * N_ + k0 + ak);
        As[ak + 0][ar] = av.x; As[ak + 1][ar] = av.y;
        As[ak + 2][ar] = av.z; As[ak + 3][ar] = av.w;
        float4 bv = *(const float4*)(Bmat + (size_t)(k0 + kr) * E_ + bn + kn);
        *(float4*)&Bs[kr][kn] = bv;
        __syncthreads();
#pragma unroll
        for (int kk = 0; kk < 16; ++kk) {
            float4 a4 = *(const float4*)&As[kk][ty << 2];
            float4 b4 = *(const float4*)&Bs[kk][tx << 2];
            float am[4] = {a4.x, a4.y, a4.z, a4.w};
            float bb[4] = {b4.x, b4.y, b4.z, b4.w};
#pragma unroll
            for (int i = 0; i < 4; ++i)
#pragma unroll
                for (int j = 0; j < 4; ++j)
                    acc[i][j] = fmaf(am[i], bb[j], acc[i][j]);
        }
        __syncthreads();
    }
#pragma unroll
    for (int i = 0; i < 4; ++i) {
        int row = b * N_ + bm + (ty << 2) + i;
        int col = which * 1024 + bn + (tx << 2);
        store4bf(&Abuf[(size_t)row * 2048 + col], acc[i][0], acc[i][1], acc[i][2], acc[i][3]);
    }
}

// ---------------------------------------------------------------------------
// Fused encoder step: gi = a@Wih^T, gh = h@Whh^T, gates, h_next (fp32).
__global__ __launch_bounds__(256)
void enc_fused_kernel(const bf16* __restrict__ Aab, const float* __restrict__ Wih,
                      const float* __restrict__ Whh, const float* __restrict__ Hcur,
                      float* __restrict__ Hnext)
{
    __shared__ float As[16][68];
    __shared__ float Bs[3][16][68];
    const int t = threadIdx.x;
    const int tx = t & 15, ty = t >> 4;
    const int bm = blockIdx.x * 64;
    const int bn = blockIdx.y * 64;
    const int ar = t >> 2, ak = (t & 3) << 2;
    float gi[3][4][4] = {};
    float gh[3][4][4] = {};

    for (int k0 = 0; k0 < 2048; k0 += 16) {
        float4 av = load4bf(Aab + (size_t)(bm + ar) * 2048 + k0 + ak);
        As[ak + 0][ar] = av.x; As[ak + 1][ar] = av.y;
        As[ak + 2][ar] = av.z; As[ak + 3][ar] = av.w;
#pragma unroll
        for (int c = 0; c < 3; ++c) {
            float4 bv = *(const float4*)(Wih + (size_t)(c * 1024 + bn + ar) * 2048 + k0 + ak);
            Bs[c][ak + 0][ar] = bv.x; Bs[c][ak + 1][ar] = bv.y;
            Bs[c][ak + 2][ar] = bv.z; Bs[c][ak + 3][ar] = bv.w;
        }
        __syncthreads();
#pragma unroll
        for (int kk = 0; kk < 16; ++kk) {
            float4 a4 = *(const float4*)&As[kk][ty << 2];
            float am[4] = {a4.x, a4.y, a4.z, a4.w};
#pragma unroll
            for (int c = 0; c < 3; ++c) {
                float4 b4 = *(const float4*)&Bs[c][kk][tx << 2];
                float bb[4] = {b4.x, b4.y, b4.z, b4.w};
#pragma unroll
                for (int i = 0; i < 4; ++i)
#pragma unroll
                    for (int j = 0; j < 4; ++j)
                        gi[c][i][j] = fmaf(am[i], bb[j], gi[c][i][j]);
            }
        }
        __syncthreads();
    }
    for (int k0 = 0; k0 < 1024; k0 += 16) {
        float4 av = *(const float4*)(Hcur + (size_t)(bm + ar) * 1024 + k0 + ak);
        As[ak + 0][ar] = av.x; As[ak + 1][ar] = av.y;
        As[ak + 2][ar] = av.z; As[ak + 3][ar] = av.w;
#pragma unroll
        for (int c = 0; c < 3; ++c) {
            float4 bv = *(const float4*)(Whh + (size_t)(c * 1024 + bn + ar) * 1024 + k0 + ak);
            Bs[c][ak + 0][ar] = bv.x; Bs[c][ak + 1][ar] = bv.y;
            Bs[c][ak + 2][ar] = bv.z; Bs[c][ak + 3][ar] = bv.w;
        }
        __syncthreads();
#pragma unroll
        for (int kk = 0; kk < 16; ++kk) {
            float4 a4 = *(const float4*)&As[kk][ty << 2];
            float am[4] = {a4.x, a4.y, a4.z, a4.w};
#pragma unroll
            for (int c = 0; c < 3; ++c) {
                float4 b4 = *(const float4*)&Bs[c][kk][tx << 2];
                float bb[4] = {b4.x, b4.y, b4.z, b4.w};
#pragma unroll
                for (int i = 0; i < 4; ++i)
#pragma unroll
                    for (int j = 0; j < 4; ++j)
                        gh[c][i][j] = fmaf(am[i], bb[j], gh[c][i][j]);
            }
        }
        __syncthreads();
    }
#pragma unroll
    for (int i = 0; i < 4; ++i) {
        int row = bm + (ty << 2) + i;
        int col = bn + (tx << 2);
        float4 h4 = *(const float4*)(Hcur + (size_t)row * 1024 + col);
        float ho[4] = {h4.x, h4.y, h4.z, h4.w};
        float o[4];
#pragma unroll
        for (int j = 0; j < 4; ++j) {
            float r = safe_sigm(gi[0][i][j] + gh[0][i][j]);
            float z = safe_sigm(gi[1][i][j] + gh[1][i][j]);
            float n = safe_tanh(gi[2][i][j] + r * gh[2][i][j]);
            o[j] = (1.0f - z) * n + z * ho[j];
        }
        *(float4*)(Hnext + (size_t)row * 1024 + col) = make_float4(o[0], o[1], o[2], o[3]);
    }
}

// ---------------------------------------------------------------------------
__global__ __launch_bounds__(128)
void vnva_kernel(const float* __restrict__ vnf_now, const float* __restrict__ vnf_all,
                 const float* __restrict__ Wn, const float* __restrict__ Wa,
                 float* __restrict__ vn, float* __restrict__ va)
{
    int b = blockIdx.x, t = threadIdx.x;
    if (t < 64) {
        float s = 0.f;
#pragma unroll
        for (int k = 0; k < 16; ++k) s = fmaf(vnf_now[b * 16 + k], Wn[k * 64 + t], s);
        vn[b * 64 + t] = s;
    } else {
        int d = t - 64;
        float s = 0.f;
#pragma unroll
        for (int k = 0; k < 16; ++k) s = fmaf(vnf_all[b * 16 + k], Wa[k * 64 + d], s);
        va[b * 64 + d] = s;
    }
}

// concat(row,1216) = [ enc_out(1024) | npos(64) | va(64) | vn(64) ] -> bf16
__global__ __launch_bounds__(256)
void concat_kernel(const float* __restrict__ H, const float* __restrict__ pos_enc,
                   const int* __restrict__ from_node, const float* __restrict__ va,
                   const float* __restrict__ vn, bf16* __restrict__ Cc)
{
    int row = blockIdx.x;
    int b = row >> 8;
    int fn = from_node[b];
    bf16* dst = Cc + (size_t)row * 1216;
    for (int c = threadIdx.x; c < 1216; c += 256) {
        float v;
        if (c < 1024)      v = H[(size_t)row * 1024 + c];
        else if (c < 1088) v = pos_enc[fn * 64 + (c - 1024)];
        else if (c < 1152) v = va[b * 64 + (c - 1088)];
        else               v = vn[b * 64 + (c - 1152)];
        dst[c] = __float2bfloat16(v);
    }
}

// ---------------------------------------------------------------------------
// Fused decoder: gi2 = concat@dgru_Wih^T + bih; h0=0 so gh=bhh; hidden=(1-z)*n (fp32)
__global__ __launch_bounds__(256)
void dec_fused_kernel(const bf16* __restrict__ Cc, const float* __restrict__ Wih,
                      const float* __restrict__ bih, const float* __restrict__ bhh,
                      float* __restrict__ hidden)
{
    __shared__ float As[16][68];
    __shared__ float Bs[3][16][68];
    const int t = threadIdx.x;
    const int tx = t & 15, ty = t >> 4;
    const int bm = blockIdx.x * 64;
    const int bn = blockIdx.y * 64;
    const int ar = t >> 2, ak = (t & 3) << 2;
    float acc[3][4][4] = {};
    for (int k0 = 0; k0 < 1216; k0 += 16) {
        float4 av = load4bf(Cc + (size_t)(bm + ar) * 1216 + k0 + ak);
        As[ak + 0][ar] = av.x; As[ak + 1][ar] = av.y;
        As[ak + 2][ar] = av.z; As[ak + 3][ar] = av.w;
#pragma unroll
        for (int c = 0; c < 3; ++c) {
            float4 bv = *(const float4*)(Wih + (size_t)(c * 2048 + bn + ar) * 1216 + k0 + ak);
            Bs[c][ak + 0][ar] = bv.x; Bs[c][ak + 1][ar] = bv.y;
            Bs[c][ak + 2][ar] = bv.z; Bs[c][ak + 3][ar] = bv.w;
        }
        __syncthreads();
#pragma unroll
        for (int kk = 0; kk < 16; ++kk) {
            float4 a4 = *(const float4*)&As[kk][ty << 2];
            float am[4] = {a4.x, a4.y, a4.z, a4.w};
#pragma unroll
            for (int c = 0; c < 3; ++c) {
                float4 b4 = *(const float4*)&Bs[c][kk][tx << 2];
                float bb[4] = {b4.x, b4.y, b4.z, b4.w};
#pragma unroll
                for (int i = 0; i < 4; ++i)
#pragma unroll
                    for (int j = 0; j < 4; ++j)
                        acc[c][i][j] = fmaf(am[i], bb[j], acc[c][i][j]);
            }
        }
        __syncthreads();
    }
    const int col = bn + (tx << 2);
    float4 bri = *(const float4*)(bih + col);
    float4 bzi = *(const float4*)(bih + 2048 + col);
    float4 bni = *(const float4*)(bih + 4096 + col);
    float4 brh = *(const float4*)(bhh + col);
    float4 bzh = *(const float4*)(bhh + 2048 + col);
    float4 bnh = *(const float4*)(bhh + 4096 + col);
    float bri_[4] = {bri.x, bri.y, bri.z, bri.w}, bzi_[4] = {bzi.x, bzi.y, bzi.z, bzi.w},
          bni_[4] = {bni.x, bni.y, bni.z, bni.w}, brh_[4] = {brh.x, brh.y, brh.z, brh.w},
          bzh_[4] = {bzh.x, bzh.y, bzh.z, bzh.w}, bnh_[4] = {bnh.x, bnh.y, bnh.z, bnh.w};
#pragma unroll
    for (int i = 0; i < 4; ++i) {
        int row = bm + (ty << 2) + i;
        float o[4];
#pragma unroll
        for (int j = 0; j < 4; ++j) {
            float r = safe_sigm(acc[0][i][j] + bri_[j] + brh_[j]);
            float z = safe_sigm(acc[1][i][j] + bzi_[j] + bzh_[j]);
            float n = safe_tanh(acc[2][i][j] + bni_[j] + r * bnh_[j]);
            o[j] = (1.0f - z) * n;
        }
        *(float4*)(hidden + (size_t)row * 2048 + col) = make_float4(o[0], o[1], o[2], o[3]);
    }
}

// ---------------------------------------------------------------------------
// mid = relu(hidden(8192,2048) @ out_W1(1024,2048)^T + b1) -> bf16
__global__ __launch_bounds__(256)
void out1_kernel(const float* __restrict__ A, const float* __restrict__ Bt,
                 const float* __restrict__ bias, bf16* __restrict__ C)
{
    __shared__ float As[16][68];
    __shared__ float Bs[16][68];
    const int t = threadIdx.x;
    const int tx = t & 15, ty = t >> 4;
    const int bm = blockIdx.x * 64;
    const int bn = blockIdx.y * 64;
    const int ar = t >> 2, ak = (t & 3) << 2;
    float acc[4][4] = {};
    for (int k0 = 0; k0 < 2048; k0 += 16) {
        float4 av = *(const float4*)(A + (size_t)(bm + ar) * 2048 + k0 + ak);
        float4 bv = *(const float4*)(Bt + (size_t)(bn + ar) * 2048 + k0 + ak);
        As[ak + 0][ar] = av.x; As[ak + 1][ar] = av.y;
        As[ak + 2][ar] = av.z; As[ak + 3][ar] = av.w;
        Bs[ak + 0][ar] = bv.x; Bs[ak + 1][ar] = bv.y;
        Bs[ak + 2][ar] = bv.z; Bs[ak + 3][ar] = bv.w;
        __syncthreads();
#pragma unroll
        for (int kk = 0; kk < 16; ++kk) {
            float4 a4 = *(const float4*)&As[kk][ty << 2];
            float4 b4 = *(const float4*)&Bs[kk][tx << 2];
            float am[4] = {a4.x, a4.y, a4.z, a4.w};
            float bb[4] = {b4.x, b4.y, b4.z, b4.w};
#pragma unroll
            for (int i = 0; i < 4; ++i)
#pragma unroll
                for (int j = 0; j < 4; ++j)
                    acc[i][j] = fmaf(am[i], bb[j], acc[i][j]);
        }
        __syncthreads();
    }
    const int col = bn + (tx << 2);
    float4 b4 = *(const float4*)(bias + col);
    float bb[4] = {b4.x, b4.y, b4.z, b4.w};
#pragma unroll
    for (int i = 0; i < 4; ++i) {
        int row = bm + (ty << 2) + i;
        float o[4];
#pragma unroll
        for (int j = 0; j < 4; ++j) o[j] = fmaxf(acc[i][j] + bb[j], 0.0f);
        store4bf(&C[(size_t)row * 1024 + col], o[0], o[1], o[2], o[3]);
    }
}

// ---------------------------------------------------------------------------
__global__ __launch_bounds__(64)
void out2_kernel(const bf16* __restrict__ mid, const float* __restrict__ W2,
                 const float* __restrict__ b2, float* __restrict__ outb)
{
    int row = blockIdx.x, t = threadIdx.x;
    float s0 = 0.f, s1 = 0.f, s2 = 0.f;
    for (int k = t; k < 1024; k += 64) {
        float m = b2f(mid[(size_t)row * 1024 + k]);
        s0 = fmaf(m, W2[k], s0);
        s1 = fmaf(m, W2[1024 + k], s1);
        s2 = fmaf(m, W2[2048 + k], s2);
    }
#pragma unroll
    for (int off = 32; off > 0; off >>= 1) {
        s0 += __shfl_down(s0, off, 64);
        s1 += __shfl_down(s1, off, 64);
        s2 += __shfl_down(s2, off, 64);
    }
    if (t == 0) {
        outb[row * 3 + 0] = s0 + b2[0];
        outb[row * 3 + 1] = s1 + b2[1];
        outb[row * 3 + 2] = s2 + b2[2];
    }
}

__global__ __launch_bounds__(64)
void max_kernel(const float* __restrict__ outb, float* __restrict__ maxb)
{
    int b = blockIdx.x, t = threadIdx.x;
    float m = -3.0e38f;
    for (int i = t; i < 768; i += 64) m = fmaxf(m, outb[b * 768 + i]);
#pragma unroll
    for (int off = 32; off > 0; off >>= 1) m = fmaxf(m, __shfl_down(m, off, 64));
    if (t == 0) maxb[b] = m;
}

__global__ __launch_bounds__(256)
void mask_kernel(const float* __restrict__ outb, const float* __restrict__ maxb,
                 const int* __restrict__ mask, float* __restrict__ out)
{
    int idx = blockIdx.x * 256 + threadIdx.x;
    if (idx >= BN_ * 3) return;
    int row = idx / 3, c = idx - row * 3;
    int b = row >> 8;
    float v = outb[idx] - (maxb[b] + 1.0f);
    float mf = (mask[row] == 1) ? 1.0f : 1e10f;
    v = mf * v + 1.0f;
    if (c == 0) out[row] = v;
    else        out[8192 + row * 2 + (c - 1)] = v;
}

// ---------------------------------------------------------------------------
extern "C" void kernel_launch(void* const* d_in, const int* in_sizes, int n_in,
                              void* d_out, int out_size, void* d_ws, size_t ws_size,
                              hipStream_t stream)
{
    const float* annotation = (const float*)d_in[0];
    const float* A_out      = (const float*)d_in[1];
    const float* A_in       = (const float*)d_in[2];
    const int*   from_node  = (const int*)d_in[3];
    const float* vnf_now    = (const float*)d_in[4];
    const float* vnf_all    = (const float*)d_in[5];
    const int*   mask       = (const int*)d_in[6];
    const float* anno_W     = (const float*)d_in[7];
    const float* gru_Wih    = (const float*)d_in[8];
    const float* gru_Whh    = (const float*)d_in[9];
    const float* vnf_now_W  = (const float*)d_in[10];
    const float* vnf_all_W  = (const float*)d_in[11];
    const float* dgru_Wih   = (const float*)d_in[12];
    // d_in[13] dgru_Whh dead: h0 == 0
    const float* dgru_bih   = (const float*)d_in[14];
    const float* dgru_bhh   = (const float*)d_in[15];
    const float* out_W1     = (const float*)d_in[16];
    const float* out_b1     = (const float*)d_in[17];
    const float* out_W2     = (const float*)d_in[18];
    const float* out_b2     = (const float*)d_in[19];
    const float* pos_enc    = (const float*)d_in[20];
    float* out = (float*)d_out;

    // ws (~33.8 MB, proven safe in round 4): bf16 Abuf + small fp32 buffers
    bf16*  Abuf = (bf16*)d_ws;                                   // 8192*2048 bf16
    float* fbuf = (float*)((char*)d_ws + (size_t)8192 * 2048 * sizeof(bf16));
    float* vnb  = fbuf;            // 32*64
    float* vab  = vnb + 2048;      // 32*64
    float* outb = vab + 2048;      // 8192*3
    float* maxb = outb + 24576;    // 32

    // fp32 H ping-pong inside d_out's hidden slot (16.7M floats = exactly 2 H's)
    float* hidden = out + 24576;
    float* H0 = hidden;
    float* H1 = H0 + (size_t)8192 * 1024;
    bf16* Cc  = Abuf;              // concat 8192x1216 bf16 (after a dead)
    bf16* mid = Abuf;              // 8192x1024 bf16 (after concat dead)

    anno_kernel<<<8192, 256, 0, stream>>>(annotation, anno_W, H0);

    const float* hc = H0;
    float* hn = H1;
    for (int s = 0; s < 5; ++s) {
        bmm_kernel<<<dim3(4, 16, 64), 256, 0, stream>>>(A_out, A_in, hc, Abuf);
        enc_fused_kernel<<<dim3(128, 16), 256, 0, stream>>>(Abuf, gru_Wih, gru_Whh, hc, hn);
        float* tmp = (float*)hc; hc = hn; hn = tmp;
    }
    // hc == H1 after 5 steps

    vnva_kernel<<<32, 128, 0, stream>>>(vnf_now, vnf_all, vnf_now_W, vnf_all_W, vnb, vab);
    concat_kernel<<<8192, 256, 0, stream>>>(hc, pos_enc, from_node, vab, vnb, Cc);
    dec_fused_kernel<<<dim3(128, 32), 256, 0, stream>>>(Cc, dgru_Wih, dgru_bih, dgru_bhh, hidden);
    out1_kernel<<<dim3(128, 16), 256, 0, stream>>>(hidden, out_W1, out_b1, mid);
    out2_kernel<<<8192, 64, 0, stream>>>(mid, out_W2, out_b2, outb);
    max_kernel<<<32, 64, 0, stream>>>(outb, maxb);
    mask_kernel<<<96, 256, 0, stream>>>(outb, maxb, mask, out);
}

// Round 6
// 3937.796 us; speedup vs baseline: 2.9494x; 2.9494x over previous
//
#include <hip/hip_runtime.h>
#include <hip/hip_bf16.h>
#include <math.h>

#define B_ 32
#define N_ 256
#define E_ 1024
#define BN_ 8192

typedef __hip_bfloat16 bf16;
typedef __bf16 bf8v __attribute__((ext_vector_type(8)));
typedef float  f4v  __attribute__((ext_vector_type(4)));

__device__ __forceinline__ float b2f(bf16 v) {
    unsigned short u = *(unsigned short*)&v;
    return __uint_as_float(((unsigned)u) << 16);
}
__device__ __forceinline__ unsigned short f2bu(float f) {
    bf16 h = __float2bfloat16(f);
    return *(unsigned short*)&h;
}
__device__ __forceinline__ float4 load4bf(const bf16* p) {
    ushort4 u = *(const ushort4*)p;
    return make_float4(__uint_as_float((unsigned)u.x << 16),
                       __uint_as_float((unsigned)u.y << 16),
                       __uint_as_float((unsigned)u.z << 16),
                       __uint_as_float((unsigned)u.w << 16));
}
__device__ __forceinline__ void store4bf(bf16* p, float a, float b, float c, float d) {
    ushort4 u = make_ushort4(f2bu(a), f2bu(b), f2bu(c), f2bu(d));
    *(ushort4*)p = u;
}
__device__ __forceinline__ float safe_sigm(float x) {
    x = fminf(fmaxf(x, -40.0f), 40.0f);
    return 1.0f / (1.0f + expf(-x));
}
__device__ __forceinline__ float safe_tanh(float x) {
    x = fminf(fmaxf(x, -15.0f), 15.0f);
    float t = expf(2.0f * x);
    return (t - 1.0f) / (t + 1.0f);
}

// ---------------------------------------------------------------------------
// fp32 -> bf16 weight conversion prepass (vectorized)
__global__ __launch_bounds__(256)
void w2bf_kernel(const float* __restrict__ src, bf16* __restrict__ dst, int n4)
{
    int i = blockIdx.x * 256 + threadIdx.x;
    if (i < n4) {
        float4 v = ((const float4*)src)[i];
        store4bf(dst + (size_t)i * 4, v.x, v.y, v.z, v.w);
    }
}

// ---------------------------------------------------------------------------
// h0 = annotation(8192,18) @ anno_W(18,1024) -> fp32
__global__ __launch_bounds__(256)
void anno_kernel(const float* __restrict__ anno, const float* __restrict__ W,
                 float* __restrict__ H)
{
    __shared__ float s[18];
    int row = blockIdx.x;
    if (threadIdx.x < 18) s[threadIdx.x] = anno[row * 18 + threadIdx.x];
    __syncthreads();
    for (int j = threadIdx.x; j < 1024; j += 256) {
        float acc = 0.0f;
#pragma unroll
        for (int k = 0; k < 18; ++k) acc = fmaf(s[k], W[k * 1024 + j], acc);
        H[(size_t)row * 1024 + j] = acc;
    }
}

// ---------------------------------------------------------------------------
// a = [A_out@H | A_in@H] per batch -> Abuf(8192,2048) bf16
__global__ __launch_bounds__(256)
void bmm_kernel(const float* __restrict__ Aout, const float* __restrict__ Ain,
                const float* __restrict__ H, bf16* __restrict__ Abuf)
{
    __shared__ float As[16][68];
    __shared__ float Bs[16][68];
    const int z = blockIdx.z;
    const int b = z >> 1, which = z & 1;
    const float* Amat = (which ? Ain : Aout) + (size_t)b * N_ * N_;
    const float* Bmat = H + (size_t)b * N_ * E_;
    const int t = threadIdx.x;
    const int tx = t & 15, ty = t >> 4;
    const int bm = blockIdx.x * 64;
    const int bn = blockIdx.y * 64;
    const int ar = t >> 2, ak = (t & 3) << 2;
    const int kr = t >> 4, kn = (t & 15) << 2;
    float acc[4][4] = {};
    for (int k0 = 0; k0 < N_; k0 += 16) {
        float4 av = *(const float4*)(Amat + (size_t)(bm + ar) * N_ + k0 + ak);
        As[ak + 0][ar] = av.x; As[ak + 1][ar] = av.y;
        As[ak + 2][ar] = av.z; As[ak + 3][ar] = av.w;
        float4 bv = *(const float4*)(Bmat + (size_t)(k0 + kr) * E_ + bn + kn);
        *(float4*)&Bs[kr][kn] = bv;
        __syncthreads();
#pragma unroll
        for (int kk = 0; kk < 16; ++kk) {
            float4 a4 = *(const float4*)&As[kk][ty << 2];
            float4 b4 = *(const float4*)&Bs[kk][tx << 2];
            float am[4] = {a4.x, a4.y, a4.z, a4.w};
            float bb[4] = {b4.x, b4.y, b4.z, b4.w};
#pragma unroll
            for (int i = 0; i < 4; ++i)
#pragma unroll
                for (int j = 0; j < 4; ++j)
                    acc[i][j] = fmaf(am[i], bb[j], acc[i][j]);
        }
        __syncthreads();
    }
#pragma unroll
    for (int i = 0; i < 4; ++i) {
        int row = b * N_ + bm + (ty << 2) + i;
        int col = which * 1024 + bn + (tx << 2);
        store4bf(&Abuf[(size_t)row * 2048 + col], acc[i][0], acc[i][1], acc[i][2], acc[i][3]);
    }
}

// ---------------------------------------------------------------------------
// MFMA encoder step: gi = a@Wih^T (3 sets, K=2048), gh = h@Whh^T (3 sets, K=1024),
// fused GRU gates -> Hnext (fp32). Block tile 64x64, 4 waves @ 32x32,
// mfma_f32_16x16x32_bf16. LDS chunk-swizzle for conflict-free b128 frag reads.
__global__ __launch_bounds__(256)
void enc_mfma_kernel(const bf16* __restrict__ Aab, const bf16* __restrict__ Wihb,
                     const bf16* __restrict__ Whhb, const float* __restrict__ Hcur,
                     float* __restrict__ Hnext)
{
    __shared__ bf16 As[64 * 32];
    __shared__ bf16 Ws[3][64 * 32];
    const int t = threadIdx.x;
    const int lane = t & 63, w = t >> 6;
    const int wm = (w >> 1) * 32, wn = (w & 1) * 32;
    const int bm = blockIdx.x * 64, bn = blockIdx.y * 64;
    const int quad = lane >> 4, fr = lane & 15;

    // staging coords: thread t stages 8 bf16 into LDS slot (srow, slot);
    // the slot holds global k-chunk g = (slot + (srow>>1)) & 3 (bank swizzle)
    const int srow = t >> 2, slot = t & 3;
    const int g = (slot + ((srow >> 1) & 3)) & 3;
    const int lds_off = srow * 32 + slot * 8;

    f4v gi[3][2][2];
    f4v gh[3][2][2];
#pragma unroll
    for (int c = 0; c < 3; ++c)
#pragma unroll
        for (int i = 0; i < 2; ++i)
#pragma unroll
            for (int j = 0; j < 2; ++j) {
                gi[c][i][j] = (f4v){0.f, 0.f, 0.f, 0.f};
                gh[c][i][j] = (f4v){0.f, 0.f, 0.f, 0.f};
            }

    // frag read offsets (swizzled): slot for (row, chunk=quad) = (quad - (row>>1)) & 3
    int arow[2], aoff[2], boff[3][2];
#pragma unroll
    for (int i = 0; i < 2; ++i) {
        arow[i] = wm + 16 * i + fr;
        int s = (quad - ((arow[i] >> 1) & 3)) & 3;
        aoff[i] = arow[i] * 32 + s * 8;
    }
#pragma unroll
    for (int j = 0; j < 2; ++j) {
        int n = wn + 16 * j + fr;
        int s = (quad - ((n >> 1) & 3)) & 3;
        boff[0][j] = n * 32 + s * 8;
    }

    // ---- phase 1: gi over a, K = 2048 ----
    {
        const bf16* Ap = Aab + (size_t)(bm + srow) * 2048 + g * 8;
        const bf16* W0 = Wihb + (size_t)(0 * 1024 + bn + srow) * 2048 + g * 8;
        const bf16* W1 = Wihb + (size_t)(1 * 1024 + bn + srow) * 2048 + g * 8;
        const bf16* W2 = Wihb + (size_t)(2 * 1024 + bn + srow) * 2048 + g * 8;
        for (int k0 = 0; k0 < 2048; k0 += 32) {
            float4 av = *(const float4*)(Ap + k0);
            float4 w0 = *(const float4*)(W0 + k0);
            float4 w1 = *(const float4*)(W1 + k0);
            float4 w2 = *(const float4*)(W2 + k0);
            __syncthreads();
            *(float4*)(As + lds_off) = av;
            *(float4*)(Ws[0] + lds_off) = w0;
            *(float4*)(Ws[1] + lds_off) = w1;
            *(float4*)(Ws[2] + lds_off) = w2;
            __syncthreads();
            bf8v af0 = *(const bf8v*)(As + aoff[0]);
            bf8v af1 = *(const bf8v*)(As + aoff[1]);
#pragma unroll
            for (int c = 0; c < 3; ++c) {
#pragma unroll
                for (int j = 0; j < 2; ++j) {
                    bf8v bv = *(const bf8v*)(Ws[c] + boff[0][j]);
                    gi[c][0][j] = __builtin_amdgcn_mfma_f32_16x16x32_bf16(af0, bv, gi[c][0][j], 0, 0, 0);
                    gi[c][1][j] = __builtin_amdgcn_mfma_f32_16x16x32_bf16(af1, bv, gi[c][1][j], 0, 0, 0);
                }
            }
        }
    }
    // ---- phase 2: gh over h (fp32 -> bf16 inline), K = 1024 ----
    {
        const float* Hp = Hcur + (size_t)(bm + srow) * 1024 + g * 8;
        const bf16* W0 = Whhb + (size_t)(0 * 1024 + bn + srow) * 1024 + g * 8;
        const bf16* W1 = Whhb + (size_t)(1 * 1024 + bn + srow) * 1024 + g * 8;
        const bf16* W2 = Whhb + (size_t)(2 * 1024 + bn + srow) * 1024 + g * 8;
        for (int k0 = 0; k0 < 1024; k0 += 32) {
            float4 h0 = *(const float4*)(Hp + k0);
            float4 h1 = *(const float4*)(Hp + k0 + 4);
            float4 w0 = *(const float4*)(W0 + k0);
            float4 w1 = *(const float4*)(W1 + k0);
            float4 w2 = *(const float4*)(W2 + k0);
            uint4 pk;
            pk.x = (unsigned)f2bu(h0.x) | ((unsigned)f2bu(h0.y) << 16);
            pk.y = (unsigned)f2bu(h0.z) | ((unsigned)f2bu(h0.w) << 16);
            pk.z = (unsigned)f2bu(h1.x) | ((unsigned)f2bu(h1.y) << 16);
            pk.w = (unsigned)f2bu(h1.z) | ((unsigned)f2bu(h1.w) << 16);
            __syncthreads();
            *(uint4*)(As + lds_off) = pk;
            *(float4*)(Ws[0] + lds_off) = w0;
            *(float4*)(Ws[1] + lds_off) = w1;
            *(float4*)(Ws[2] + lds_off) = w2;
            __syncthreads();
            bf8v af0 = *(const bf8v*)(As + aoff[0]);
            bf8v af1 = *(const bf8v*)(As + aoff[1]);
#pragma unroll
            for (int c = 0; c < 3; ++c) {
#pragma unroll
                for (int j = 0; j < 2; ++j) {
                    bf8v bv = *(const bf8v*)(Ws[c] + boff[0][j]);
                    gh[c][0][j] = __builtin_amdgcn_mfma_f32_16x16x32_bf16(af0, bv, gh[c][0][j], 0, 0, 0);
                    gh[c][1][j] = __builtin_amdgcn_mfma_f32_16x16x32_bf16(af1, bv, gh[c][1][j], 0, 0, 0);
                }
            }
        }
    }
    // ---- gates: C/D layout col = lane&15, row = quad*4 + reg ----
#pragma unroll
    for (int i = 0; i < 2; ++i) {
#pragma unroll
        for (int j = 0; j < 2; ++j) {
#pragma unroll
            for (int r = 0; r < 4; ++r) {
                int row = bm + wm + 16 * i + quad * 4 + r;
                int col = bn + wn + 16 * j + fr;
                float hv = Hcur[(size_t)row * 1024 + col];
                float rr = safe_sigm(gi[0][i][j][r] + gh[0][i][j][r]);
                float zz = safe_sigm(gi[1][i][j][r] + gh[1][i][j][r]);
                float nn = safe_tanh(gi[2][i][j][r] + rr * gh[2][i][j][r]);
                Hnext[(size_t)row * 1024 + col] = (1.0f - zz) * nn + zz * hv;
            }
        }
    }
}

// ---------------------------------------------------------------------------
__global__ __launch_bounds__(128)
void vnva_kernel(const float* __restrict__ vnf_now, const float* __restrict__ vnf_all,
                 const float* __restrict__ Wn, const float* __restrict__ Wa,
                 float* __restrict__ vn, float* __restrict__ va)
{
    int b = blockIdx.x, t = threadIdx.x;
    if (t < 64) {
        float s = 0.f;
#pragma unroll
        for (int k = 0; k < 16; ++k) s = fmaf(vnf_now[b * 16 + k], Wn[k * 64 + t], s);
        vn[b * 64 + t] = s;
    } else {
        int d = t - 64;
        float s = 0.f;
#pragma unroll
        for (int k = 0; k < 16; ++k) s = fmaf(vnf_all[b * 16 + k], Wa[k * 64 + d], s);
        va[b * 64 + d] = s;
    }
}

// concat(row,1216) = [ enc_out(1024) | npos(64) | va(64) | vn(64) ] -> bf16
__global__ __launch_bounds__(256)
void concat_kernel(const float* __restrict__ H, const float* __restrict__ pos_enc,
                   const int* __restrict__ from_node, const float* __restrict__ va,
                   const float* __restrict__ vn, bf16* __restrict__ Cc)
{
    int row = blockIdx.x;
    int b = row >> 8;
    int fn = from_node[b];
    bf16* dst = Cc + (size_t)row * 1216;
    for (int c = threadIdx.x; c < 1216; c += 256) {
        float v;
        if (c < 1024)      v = H[(size_t)row * 1024 + c];
        else if (c < 1088) v = pos_enc[fn * 64 + (c - 1024)];
        else if (c < 1152) v = va[b * 64 + (c - 1088)];
        else               v = vn[b * 64 + (c - 1152)];
        dst[c] = __float2bfloat16(v);
    }
}

// ---------------------------------------------------------------------------
// Fused decoder: gi2 = concat@dgru_Wih^T + bih; h0=0 so gh=bhh; hidden=(1-z)*n (fp32)
__global__ __launch_bounds__(256)
void dec_fused_kernel(const bf16* __restrict__ Cc, const float* __restrict__ Wih,
                      const float* __restrict__ bih, const float* __restrict__ bhh,
                      float* __restrict__ hidden)
{
    __shared__ float As[16][68];
    __shared__ float Bs[3][16][68];
    const int t = threadIdx.x;
    const int tx = t & 15, ty = t >> 4;
    const int bm = blockIdx.x * 64;
    const int bn = blockIdx.y * 64;
    const int ar = t >> 2, ak = (t & 3) << 2;
    float acc[3][4][4] = {};
    for (int k0 = 0; k0 < 1216; k0 += 16) {
        float4 av = load4bf(Cc + (size_t)(bm + ar) * 1216 + k0 + ak);
        As[ak + 0][ar] = av.x; As[ak + 1][ar] = av.y;
        As[ak + 2][ar] = av.z; As[ak + 3][ar] = av.w;
#pragma unroll
        for (int c = 0; c < 3; ++c) {
            float4 bv = *(const float4*)(Wih + (size_t)(c * 2048 + bn + ar) * 1216 + k0 + ak);
            Bs[c][ak + 0][ar] = bv.x; Bs[c][ak + 1][ar] = bv.y;
            Bs[c][ak + 2][ar] = bv.z; Bs[c][ak + 3][ar] = bv.w;
        }
        __syncthreads();
#pragma unroll
        for (int kk = 0; kk < 16; ++kk) {
            float4 a4 = *(const float4*)&As[kk][ty << 2];
            float am[4] = {a4.x, a4.y, a4.z, a4.w};
#pragma unroll
            for (int c = 0; c < 3; ++c) {
                float4 b4 = *(const float4*)&Bs[c][kk][tx << 2];
                float bb[4] = {b4.x, b4.y, b4.z, b4.w};
#pragma unroll
                for (int i = 0; i < 4; ++i)
#pragma unroll
                    for (int j = 0; j < 4; ++j)
                        acc[c][i][j] = fmaf(am[i], bb[j], acc[c][i][j]);
            }
        }
        __syncthreads();
    }
    const int col = bn + (tx << 2);
    float4 bri = *(const float4*)(bih + col);
    float4 bzi = *(const float4*)(bih + 2048 + col);
    float4 bni = *(const float4*)(bih + 4096 + col);
    float4 brh = *(const float4*)(bhh + col);
    float4 bzh = *(const float4*)(bhh + 2048 + col);
    float4 bnh = *(const float4*)(bhh + 4096 + col);
    float bri_[4] = {bri.x, bri.y, bri.z, bri.w}, bzi_[4] = {bzi.x, bzi.y, bzi.z, bzi.w},
          bni_[4] = {bni.x, bni.y, bni.z, bni.w}, brh_[4] = {brh.x, brh.y, brh.z, brh.w},
          bzh_[4] = {bzh.x, bzh.y, bzh.z, bzh.w}, bnh_[4] = {bnh.x, bnh.y, bnh.z, bnh.w};
#pragma unroll
    for (int i = 0; i < 4; ++i) {
        int row = bm + (ty << 2) + i;
        float o[4];
#pragma unroll
        for (int j = 0; j < 4; ++j) {
            float r = safe_sigm(acc[0][i][j] + bri_[j] + brh_[j]);
            float z = safe_sigm(acc[1][i][j] + bzi_[j] + bzh_[j]);
            float n = safe_tanh(acc[2][i][j] + bni_[j] + r * bnh_[j]);
            o[j] = (1.0f - z) * n;
        }
        *(float4*)(hidden + (size_t)row * 2048 + col) = make_float4(o[0], o[1], o[2], o[3]);
    }
}

// ---------------------------------------------------------------------------
// mid = relu(hidden(8192,2048) @ out_W1(1024,2048)^T + b1) -> bf16
__global__ __launch_bounds__(256)
void out1_kernel(const float* __restrict__ A, const float* __restrict__ Bt,
                 const float* __restrict__ bias, bf16* __restrict__ C)
{
    __shared__ float As[16][68];
    __shared__ float Bs[16][68];
    const int t = threadIdx.x;
    const int tx = t & 15, ty = t >> 4;
    const int bm = blockIdx.x * 64;
    const int bn = blockIdx.y * 64;
    const int ar = t >> 2, ak = (t & 3) << 2;
    float acc[4][4] = {};
    for (int k0 = 0; k0 < 2048; k0 += 16) {
        float4 av = *(const float4*)(A + (size_t)(bm + ar) * 2048 + k0 + ak);
        float4 bv = *(const float4*)(Bt + (size_t)(bn + ar) * 2048 + k0 + ak);
        As[ak + 0][ar] = av.x; As[ak + 1][ar] = av.y;
        As[ak + 2][ar] = av.z; As[ak + 3][ar] = av.w;
        Bs[ak + 0][ar] = bv.x; Bs[ak + 1][ar] = bv.y;
        Bs[ak + 2][ar] = bv.z; Bs[ak + 3][ar] = bv.w;
        __syncthreads();
#pragma unroll
        for (int kk = 0; kk < 16; ++kk) {
            float4 a4 = *(const float4*)&As[kk][ty << 2];
            float4 b4 = *(const float4*)&Bs[kk][tx << 2];
            float am[4] = {a4.x, a4.y, a4.z, a4.w};
            float bb[4] = {b4.x, b4.y, b4.z, b4.w};
#pragma unroll
            for (int i = 0; i < 4; ++i)
#pragma unroll
                for (int j = 0; j < 4; ++j)
                    acc[i][j] = fmaf(am[i], bb[j], acc[i][j]);
        }
        __syncthreads();
    }
    const int col = bn + (tx << 2);
    float4 b4 = *(const float4*)(bias + col);
    float bb[4] = {b4.x, b4.y, b4.z, b4.w};
#pragma unroll
    for (int i = 0; i < 4; ++i) {
        int row = bm + (ty << 2) + i;
        float o[4];
#pragma unroll
        for (int j = 0; j < 4; ++j) o[j] = fmaxf(acc[i][j] + bb[j], 0.0f);
        store4bf(&C[(size_t)row * 1024 + col], o[0], o[1], o[2], o[3]);
    }
}

// ---------------------------------------------------------------------------
__global__ __launch_bounds__(64)
void out2_kernel(const bf16* __restrict__ mid, const float* __restrict__ W2,
                 const float* __restrict__ b2, float* __restrict__ outb)
{
    int row = blockIdx.x, t = threadIdx.x;
    float s0 = 0.f, s1 = 0.f, s2 = 0.f;
    for (int k = t; k < 1024; k += 64) {
        float m = b2f(mid[(size_t)row * 1024 + k]);
        s0 = fmaf(m, W2[k], s0);
        s1 = fmaf(m, W2[1024 + k], s1);
        s2 = fmaf(m, W2[2048 + k], s2);
    }
#pragma unroll
    for (int off = 32; off > 0; off >>= 1) {
        s0 += __shfl_down(s0, off, 64);
        s1 += __shfl_down(s1, off, 64);
        s2 += __shfl_down(s2, off, 64);
    }
    if (t == 0) {
        outb[row * 3 + 0] = s0 + b2[0];
        outb[row * 3 + 1] = s1 + b2[1];
        outb[row * 3 + 2] = s2 + b2[2];
    }
}

__global__ __launch_bounds__(64)
void max_kernel(const float* __restrict__ outb, float* __restrict__ maxb)
{
    int b = blockIdx.x, t = threadIdx.x;
    float m = -3.0e38f;
    for (int i = t; i < 768; i += 64) m = fmaxf(m, outb[b * 768 + i]);
#pragma unroll
    for (int off = 32; off > 0; off >>= 1) m = fmaxf(m, __shfl_down(m, off, 64));
    if (t == 0) maxb[b] = m;
}

__global__ __launch_bounds__(256)
void mask_kernel(const float* __restrict__ outb, const float* __restrict__ maxb,
                 const int* __restrict__ mask, float* __restrict__ out)
{
    int idx = blockIdx.x * 256 + threadIdx.x;
    if (idx >= BN_ * 3) return;
    int row = idx / 3, c = idx - row * 3;
    int b = row >> 8;
    float v = outb[idx] - (maxb[b] + 1.0f);
    float mf = (mask[row] == 1) ? 1.0f : 1e10f;
    v = mf * v + 1.0f;
    if (c == 0) out[row] = v;
    else        out[8192 + row * 2 + (c - 1)] = v;
}

// ---------------------------------------------------------------------------
extern "C" void kernel_launch(void* const* d_in, const int* in_sizes, int n_in,
                              void* d_out, int out_size, void* d_ws, size_t ws_size,
                              hipStream_t stream)
{
    const float* annotation = (const float*)d_in[0];
    const float* A_out      = (const float*)d_in[1];
    const float* A_in       = (const float*)d_in[2];
    const int*   from_node  = (const int*)d_in[3];
    const float* vnf_now    = (const float*)d_in[4];
    const float* vnf_all    = (const float*)d_in[5];
    const int*   mask       = (const int*)d_in[6];
    const float* anno_W     = (const float*)d_in[7];
    const float* gru_Wih    = (const float*)d_in[8];
    const float* gru_Whh    = (const float*)d_in[9];
    const float* vnf_now_W  = (const float*)d_in[10];
    const float* vnf_all_W  = (const float*)d_in[11];
    const float* dgru_Wih   = (const float*)d_in[12];
    // d_in[13] dgru_Whh dead: h0 == 0
    const float* dgru_bih   = (const float*)d_in[14];
    const float* dgru_bhh   = (const float*)d_in[15];
    const float* out_W1     = (const float*)d_in[16];
    const float* out_b1     = (const float*)d_in[17];
    const float* out_W2     = (const float*)d_in[18];
    const float* out_b2     = (const float*)d_in[19];
    const float* pos_enc    = (const float*)d_in[20];
    float* out = (float*)d_out;

    // ws layout (~52.5 MB): Abuf bf16 (33.5) + Wihb bf16 (12.6) + Whhb bf16 (6.3) + small
    bf16*  Abuf = (bf16*)d_ws;                           // 8192*2048
    bf16*  Wihb = Abuf + (size_t)8192 * 2048;            // 3072*2048
    bf16*  Whhb = Wihb + (size_t)3072 * 2048;            // 3072*1024
    float* fbuf = (float*)(Whhb + (size_t)3072 * 1024);
    float* vnb  = fbuf;            // 32*64
    float* vab  = vnb + 2048;      // 32*64
    float* outb = vab + 2048;      // 8192*3
    float* maxb = outb + 24576;    // 32

    // fp32 H ping-pong inside d_out's hidden slot
    float* hidden = out + 24576;
    float* H0 = hidden;
    float* H1 = H0 + (size_t)8192 * 1024;
    bf16* Cc  = Abuf;              // concat 8192x1216 bf16 (after a dead)
    bf16* mid = Abuf;              // 8192x1024 bf16 (after concat dead)

    // weight prepass (same work every launch — graph-capture safe)
    w2bf_kernel<<<6144, 256, 0, stream>>>(gru_Wih, Wihb, 3072 * 2048 / 4);
    w2bf_kernel<<<3072, 256, 0, stream>>>(gru_Whh, Whhb, 3072 * 1024 / 4);

    anno_kernel<<<8192, 256, 0, stream>>>(annotation, anno_W, H0);

    const float* hc = H0;
    float* hn = H1;
    for (int s = 0; s < 5; ++s) {
        bmm_kernel<<<dim3(4, 16, 64), 256, 0, stream>>>(A_out, A_in, hc, Abuf);
        enc_mfma_kernel<<<dim3(128, 16), 256, 0, stream>>>(Abuf, Wihb, Whhb, hc, hn);
        float* tmp = (float*)hc; hc = hn; hn = tmp;
    }
    // hc == H1 after 5 steps

    vnva_kernel<<<32, 128, 0, stream>>>(vnf_now, vnf_all, vnf_now_W, vnf_all_W, vnb, vab);
    concat_kernel<<<8192, 256, 0, stream>>>(hc, pos_enc, from_node, vab, vnb, Cc);
    dec_fused_kernel<<<dim3(128, 32), 256, 0, stream>>>(Cc, dgru_Wih, dgru_bih, dgru_bhh, hidden);
    out1_kernel<<<dim3(128, 16), 256, 0, stream>>>(hidden, out_W1, out_b1, mid);
    out2_kernel<<<8192, 64, 0, stream>>>(mid, out_W2, out_b2, outb);
    max_kernel<<<32, 64, 0, stream>>>(outb, maxb);
    mask_kernel<<<96, 256, 0, stream>>>(outb, maxb, mask, out);
}